// Round 11
// baseline (1003.074 us; speedup 1.0000x reference)
//
#include <hip/hip_runtime.h>

#define NLEVELS 16
#define TSIZE 131072
#define TMASK (TSIZE - 1)
#define NBUCK 32768           // 8 trees x 4096 morton cells (4 bits/dim)

typedef float f32x4 __attribute__((ext_vector_type(4)));

__device__ __constant__ float RM1_TAB[16] = {
    15.f, 21.f, 29.f, 40.f, 54.f, 74.f, 101.f, 138.f,
    187.f, 255.f, 347.f, 471.f, 641.f, 871.f, 1183.f, 1607.f
};

constexpr float RM1_C[16] = {
    15.f, 21.f, 29.f, 40.f, 54.f, 74.f, 101.f, 138.f,
    187.f, 255.f, 347.f, 471.f, 641.f, 871.f, 1183.f, 1607.f
};

__device__ __forceinline__ unsigned spread4(unsigned v) {
    v = (v | (v << 4)) & 0x0C3u;
    v = (v | (v << 2)) & 0x249u;
    return v;
}

__device__ __forceinline__ unsigned bucket_key(float x, float y, float z, unsigned tree) {
    const int cx = min(max((int)((x * 0.5f + 0.5f) * 16.f), 0), 15);
    const int cy = min(max((int)((y * 0.5f + 0.5f) * 16.f), 0), 15);
    const int cz = min(max((int)((z * 0.5f + 0.5f) * 16.f), 0), 15);
    const unsigned m = spread4((unsigned)cx) | (spread4((unsigned)cy) << 1)
                     | (spread4((unsigned)cz) << 2);
    return (tree << 12) | m;
}

// ---------------- counting sort by (tree, morton12) ----------------

__global__ __launch_bounds__(256) void k_hist(const float* __restrict__ xs,
                                              const int* __restrict__ inds, int N,
                                              unsigned* __restrict__ hist) {
    const int i = blockIdx.x * 256 + threadIdx.x;
    if (i >= N) return;
    const unsigned key = bucket_key(xs[3 * i], xs[3 * i + 1], xs[3 * i + 2],
                                    (unsigned)(inds[i] & 7));
    atomicAdd(&hist[key], 1u);
}

__global__ __launch_bounds__(1024) void k_scan(const unsigned* __restrict__ hist,
                                               unsigned* __restrict__ cursor) {
    __shared__ unsigned sums[1024];
    const int t = threadIdx.x;
    const int per = NBUCK / 1024;          // 32
    unsigned s = 0;
    #pragma unroll
    for (int j = 0; j < per; ++j) s += hist[t * per + j];
    sums[t] = s;
    __syncthreads();
    for (int off = 1; off < 1024; off <<= 1) {
        const unsigned add = (t >= off) ? sums[t - off] : 0u;
        __syncthreads();
        sums[t] += add;
        __syncthreads();
    }
    unsigned run = (t == 0) ? 0u : sums[t - 1];
    #pragma unroll
    for (int j = 0; j < per; ++j) {
        cursor[t * per + j] = run;
        run += hist[t * per + j];
    }
}

__global__ __launch_bounds__(256) void k_scatter(const float* __restrict__ xs,
                                                 const int* __restrict__ inds, int N,
                                                 unsigned* __restrict__ cursor,
                                                 float4* __restrict__ sorted) {
    const int i = blockIdx.x * 256 + threadIdx.x;
    if (i >= N) return;
    const float x = xs[3 * i], y = xs[3 * i + 1], z = xs[3 * i + 2];
    const unsigned tree = (unsigned)(inds[i] & 7);
    const unsigned key = bucket_key(x, y, z, tree);
    const unsigned pos = atomicAdd(&cursor[key], 1u);
    sorted[pos] = make_float4(x, y, z, __uint_as_float(((unsigned)i) | (tree << 24)));
}

// ---------------- one level, compile-time L, NO arrays anywhere ------------

template<int L>
__device__ __forceinline__ float2 level_one(const float4 p, int tree,
                                            const float* __restrict__ params) {
    constexpr float rm1 = RM1_C[L];
    constexpr int rmax = (int)rm1;

    const float px = (p.x * 0.5f + 0.5f) * rm1;
    const float py = (p.y * 0.5f + 0.5f) * rm1;
    const float pz = (p.z * 0.5f + 0.5f) * rm1;
    const float fx = floorf(px), fy = floorf(py), fz = floorf(pz);
    const float wx = px - fx, wy = py - fy, wz = pz - fz;
    const int ix = (int)fx, iy = (int)fy, iz = (int)fz;

    const int x0 = min(max(ix, 0), rmax), x1 = min(max(ix + 1, 0), rmax);
    const int y0 = min(max(iy, 0), rmax), y1 = min(max(iy + 1, 0), rmax);
    const int z0 = min(max(iz, 0), rmax), z1 = min(max(iz + 1, 0), rmax);

    const unsigned hx0 = (unsigned)x0;
    const unsigned hx1 = (unsigned)x1;
    const unsigned hy0 = (unsigned)y0 * 2654435761u;
    const unsigned hy1 = (unsigned)y1 * 2654435761u;
    const unsigned hz0 = (unsigned)z0 * 805459861u;
    const unsigned hz1 = (unsigned)z1 * 805459861u;

    const float2* __restrict__ tbl =
        (const float2*)(params + (size_t)(tree * NLEVELS + L) * (TSIZE * 2));

    const unsigned m00 = hy0 ^ hz0;
    const unsigned m01 = hy0 ^ hz1;
    const unsigned m10 = hy1 ^ hz0;
    const unsigned m11 = hy1 ^ hz1;
    const unsigned i000 = (hx0 ^ m00) & TMASK;
    const unsigned i001 = (hx0 ^ m01) & TMASK;
    const unsigned i010 = (hx0 ^ m10) & TMASK;
    const unsigned i011 = (hx0 ^ m11) & TMASK;

    float2 f0, f1, f2, f3, f4, f5, f6, f7;   // named registers only

    // x-prime is 1: if x0 even and x1==x0+1, the two x-corners are ADJACENT
    // table entries {2j,2j+1} -> one aligned float4 covers both.
    const bool pairOK = ((x0 & 1) == 0) && (x1 == x0 + 1);
    if (pairOK) {
        const float4* __restrict__ tbl4 = (const float4*)tbl;
        const float4 q00 = tbl4[i000 >> 1];
        const float4 q01 = tbl4[i001 >> 1];
        const float4 q10 = tbl4[i010 >> 1];
        const float4 q11 = tbl4[i011 >> 1];
        f0 = (i000 & 1) ? make_float2(q00.z, q00.w) : make_float2(q00.x, q00.y);
        f4 = (i000 & 1) ? make_float2(q00.x, q00.y) : make_float2(q00.z, q00.w);
        f1 = (i001 & 1) ? make_float2(q01.z, q01.w) : make_float2(q01.x, q01.y);
        f5 = (i001 & 1) ? make_float2(q01.x, q01.y) : make_float2(q01.z, q01.w);
        f2 = (i010 & 1) ? make_float2(q10.z, q10.w) : make_float2(q10.x, q10.y);
        f6 = (i010 & 1) ? make_float2(q10.x, q10.y) : make_float2(q10.z, q10.w);
        f3 = (i011 & 1) ? make_float2(q11.z, q11.w) : make_float2(q11.x, q11.y);
        f7 = (i011 & 1) ? make_float2(q11.x, q11.y) : make_float2(q11.z, q11.w);
    } else {
        const unsigned i100 = (hx1 ^ m00) & TMASK;
        const unsigned i101 = (hx1 ^ m01) & TMASK;
        const unsigned i110 = (hx1 ^ m10) & TMASK;
        const unsigned i111 = (hx1 ^ m11) & TMASK;
        f0 = tbl[i000]; f1 = tbl[i001];
        f2 = tbl[i010]; f3 = tbl[i011];
        f4 = tbl[i100]; f5 = tbl[i101];
        f6 = tbl[i110]; f7 = tbl[i111];
    }

    const float wx0 = 1.f - wx, wy0 = 1.f - wy, wz0 = 1.f - wz;
    const float w0 = wx0 * wy0 * wz0;
    const float w1 = wx0 * wy0 * wz;
    const float w2 = wx0 * wy  * wz0;
    const float w3 = wx0 * wy  * wz;
    const float w4 = wx  * wy0 * wz0;
    const float w5 = wx  * wy0 * wz;
    const float w6 = wx  * wy  * wz0;
    const float w7 = wx  * wy  * wz;

    float a0 = 0.f, a1 = 0.f;
    a0 = fmaf(w0, f0.x, a0); a1 = fmaf(w0, f0.y, a1);
    a0 = fmaf(w1, f1.x, a0); a1 = fmaf(w1, f1.y, a1);
    a0 = fmaf(w2, f2.x, a0); a1 = fmaf(w2, f2.y, a1);
    a0 = fmaf(w3, f3.x, a0); a1 = fmaf(w3, f3.y, a1);
    a0 = fmaf(w4, f4.x, a0); a1 = fmaf(w4, f4.y, a1);
    a0 = fmaf(w5, f5.x, a0); a1 = fmaf(w5, f5.y, a1);
    a0 = fmaf(w6, f6.x, a0); a1 = fmaf(w6, f6.y, a1);
    a0 = fmaf(w7, f7.x, a0); a1 = fmaf(w7, f7.y, a1);
    return make_float2(a0, a1);
}

// ---------------- quad gather kernel ----------------
// grid(nc, 4): y = level-quad g (levels 4g..4g+3), x -> XCD-contiguous
// bijective chunk map (XCD j = x&7 gets a contiguous 1/8 of the tree/morton-
// sorted chunks). y is the SLOW dispatch dim -> at any instant all resident
// blocks share ~one quad -> per-XCD working set = 4 tables of its tree
// (<= 4 MB, L2-resident). Every XCD runs every quad on equal chunk counts ->
// equal queues, no imbalance, no rotation needed.
// Each thread writes 32 B (one HBM write granule) at n*128 + g*32: two
// back-to-back NT float4 stores -> no partial-granule amplification, no
// ws2 round-trip, no k_final.

template<int G>
__device__ __forceinline__ void quad_levels(const float4 p, int tree,
                                            const float* __restrict__ params,
                                            float2& r0, float2& r1,
                                            float2& r2, float2& r3) {
    r0 = level_one<4 * G + 0>(p, tree, params);
    r1 = level_one<4 * G + 1>(p, tree, params);
    r2 = level_one<4 * G + 2>(p, tree, params);
    r3 = level_one<4 * G + 3>(p, tree, params);
}

__global__ __launch_bounds__(256) void k_quad(const float4* __restrict__ sorted,
                                              const float* __restrict__ params,
                                              float4* __restrict__ out4,
                                              int N, int nc) {
    const int g = blockIdx.y;
    const int b = blockIdx.x;
    const int q = nc >> 3, r = nc & 7;
    const int j = b & 7;
    const int chunk = j * q + min(j, r) + (b >> 3);   // bijective [0,nc)
    const int i = chunk * 256 + (int)threadIdx.x;
    if (i >= N) return;

    const f32x4 pv = __builtin_nontemporal_load((const f32x4*)&sorted[i]);
    const float4 p = *(const float4*)&pv;
    const unsigned wbits = __float_as_uint(p.w);
    const int n = (int)(wbits & 0xFFFFFFu);
    const int tree = (int)(wbits >> 24);

    float2 r0, r1, r2, r3;
    if      (g == 0) quad_levels<0>(p, tree, params, r0, r1, r2, r3);
    else if (g == 1) quad_levels<1>(p, tree, params, r0, r1, r2, r3);
    else if (g == 2) quad_levels<2>(p, tree, params, r0, r1, r2, r3);
    else             quad_levels<3>(p, tree, params, r0, r1, r2, r3);

    const float4 o0 = make_float4(r0.x, r0.y, r1.x, r1.y);
    const float4 o1 = make_float4(r2.x, r2.y, r3.x, r3.y);
    const size_t base = (size_t)n * 8 + 2 * g;
    __builtin_nontemporal_store(*(const f32x4*)&o0, (f32x4*)&out4[base]);
    __builtin_nontemporal_store(*(const f32x4*)&o1, (f32x4*)&out4[base + 1]);
}

// ---------------- fallback (fused one-pass) ----------------

__global__ __launch_bounds__(256) void lotd_fwd_fused(
    const float* __restrict__ xs, const float* __restrict__ params,
    const int* __restrict__ inds, float* __restrict__ out, int N)
{
    const int g = blockIdx.x * 256 + threadIdx.x;
    const int n = g >> 4;
    if (n >= N) return;
    const int l = g & 15;
    const float rm1 = RM1_TAB[l];
    const int rmax = (int)rm1;
    const float x = xs[3 * n], y = xs[3 * n + 1], z = xs[3 * n + 2];
    const int tree = inds[n];
    const float px = (x * 0.5f + 0.5f) * rm1;
    const float py = (y * 0.5f + 0.5f) * rm1;
    const float pz = (z * 0.5f + 0.5f) * rm1;
    const float fx = floorf(px), fy = floorf(py), fz = floorf(pz);
    const float wx = px - fx, wy = py - fy, wz = pz - fz;
    const int ix = (int)fx, iy = (int)fy, iz = (int)fz;
    const int x0 = min(max(ix, 0), rmax), x1 = min(max(ix + 1, 0), rmax);
    const int y0 = min(max(iy, 0), rmax), y1 = min(max(iy + 1, 0), rmax);
    const int z0 = min(max(iz, 0), rmax), z1 = min(max(iz + 1, 0), rmax);
    const unsigned hx0 = (unsigned)x0, hx1 = (unsigned)x1;
    const unsigned hy0 = (unsigned)y0 * 2654435761u, hy1 = (unsigned)y1 * 2654435761u;
    const unsigned hz0 = (unsigned)z0 * 805459861u,  hz1 = (unsigned)z1 * 805459861u;
    const float2* tbl = (const float2*)(params + (size_t)(tree * NLEVELS + l) * (TSIZE * 2));
    const float2 f000 = tbl[(hx0 ^ hy0 ^ hz0) & TMASK];
    const float2 f001 = tbl[(hx0 ^ hy0 ^ hz1) & TMASK];
    const float2 f010 = tbl[(hx0 ^ hy1 ^ hz0) & TMASK];
    const float2 f011 = tbl[(hx0 ^ hy1 ^ hz1) & TMASK];
    const float2 f100 = tbl[(hx1 ^ hy0 ^ hz0) & TMASK];
    const float2 f101 = tbl[(hx1 ^ hy0 ^ hz1) & TMASK];
    const float2 f110 = tbl[(hx1 ^ hy1 ^ hz0) & TMASK];
    const float2 f111 = tbl[(hx1 ^ hy1 ^ hz1) & TMASK];
    const float wx0 = 1.f - wx, wy0 = 1.f - wy, wz0 = 1.f - wz;
    float a0 = 0.f, a1 = 0.f;
    a0 = fmaf(wx0*wy0*wz0, f000.x, a0); a1 = fmaf(wx0*wy0*wz0, f000.y, a1);
    a0 = fmaf(wx0*wy0*wz , f001.x, a0); a1 = fmaf(wx0*wy0*wz , f001.y, a1);
    a0 = fmaf(wx0*wy *wz0, f010.x, a0); a1 = fmaf(wx0*wy *wz0, f010.y, a1);
    a0 = fmaf(wx0*wy *wz , f011.x, a0); a1 = fmaf(wx0*wy *wz , f011.y, a1);
    a0 = fmaf(wx *wy0*wz0, f100.x, a0); a1 = fmaf(wx *wy0*wz0, f100.y, a1);
    a0 = fmaf(wx *wy0*wz , f101.x, a0); a1 = fmaf(wx *wy0*wz , f101.y, a1);
    a0 = fmaf(wx *wy *wz0, f110.x, a0); a1 = fmaf(wx *wy *wz0, f110.y, a1);
    a0 = fmaf(wx *wy *wz , f111.x, a0); a1 = fmaf(wx *wy *wz , f111.y, a1);
    ((float2*)out)[(size_t)n * 16 + l] = make_float2(a0, a1);
}

extern "C" void kernel_launch(void* const* d_in, const int* in_sizes, int n_in,
                              void* d_out, int out_size, void* d_ws, size_t ws_size,
                              hipStream_t stream) {
    const float* xs     = (const float*)d_in[0];
    const float* params = (const float*)d_in[1];
    const int*   inds   = (const int*)d_in[2];
    float*       out    = (float*)d_out;

    const int N = in_sizes[0] / 3;
    const int nc = (N + 255) / 256;

    const size_t hist_bytes   = (size_t)NBUCK * 4;               // 128 KB
    const size_t head_bytes   = 2 * hist_bytes;                  // hist + cursor
    const size_t sorted_bytes = ((size_t)N * 16 + 255) & ~(size_t)255;
    const size_t need = head_bytes + sorted_bytes;

    if (ws_size < need) {
        const int total = N * NLEVELS;
        lotd_fwd_fused<<<(total + 255) / 256, 256, 0, stream>>>(xs, params, inds, out, N);
        return;
    }

    unsigned* hist   = (unsigned*)d_ws;
    unsigned* cursor = (unsigned*)((char*)d_ws + hist_bytes);
    float4*   sorted = (float4*)((char*)d_ws + head_bytes);

    hipMemsetAsync(hist, 0, hist_bytes, stream);
    k_hist<<<nc, 256, 0, stream>>>(xs, inds, N, hist);
    k_scan<<<1, 1024, 0, stream>>>(hist, cursor);
    k_scatter<<<nc, 256, 0, stream>>>(xs, inds, N, cursor, sorted);

    dim3 grid(nc, 4);
    k_quad<<<grid, 256, 0, stream>>>(sorted, params, (float4*)out, N, nc);
}

// Round 12
// 848.130 us; speedup vs baseline: 1.1827x; 1.1827x over previous
//
#include <hip/hip_runtime.h>

#define NLEVELS 16
#define TSIZE 131072
#define TMASK (TSIZE - 1)
#define NBUCK 32768           // 8 trees x 4096 morton cells (4 bits/dim)

typedef float f32x4 __attribute__((ext_vector_type(4)));

__device__ __constant__ float RM1_TAB[16] = {
    15.f, 21.f, 29.f, 40.f, 54.f, 74.f, 101.f, 138.f,
    187.f, 255.f, 347.f, 471.f, 641.f, 871.f, 1183.f, 1607.f
};

constexpr float RM1_C[16] = {
    15.f, 21.f, 29.f, 40.f, 54.f, 74.f, 101.f, 138.f,
    187.f, 255.f, 347.f, 471.f, 641.f, 871.f, 1183.f, 1607.f
};

__device__ __forceinline__ unsigned spread4(unsigned v) {
    v = (v | (v << 4)) & 0x0C3u;
    v = (v | (v << 2)) & 0x249u;
    return v;
}

__device__ __forceinline__ unsigned bucket_key(float x, float y, float z, unsigned tree) {
    const int cx = min(max((int)((x * 0.5f + 0.5f) * 16.f), 0), 15);
    const int cy = min(max((int)((y * 0.5f + 0.5f) * 16.f), 0), 15);
    const int cz = min(max((int)((z * 0.5f + 0.5f) * 16.f), 0), 15);
    const unsigned m = spread4((unsigned)cx) | (spread4((unsigned)cy) << 1)
                     | (spread4((unsigned)cz) << 2);
    return (tree << 12) | m;
}

// ---------------- counting sort by (tree, morton12) ----------------

__global__ __launch_bounds__(256) void k_hist(const float* __restrict__ xs,
                                              const int* __restrict__ inds, int N,
                                              unsigned* __restrict__ hist) {
    const int i = blockIdx.x * 256 + threadIdx.x;
    if (i >= N) return;
    const unsigned key = bucket_key(xs[3 * i], xs[3 * i + 1], xs[3 * i + 2],
                                    (unsigned)(inds[i] & 7));
    atomicAdd(&hist[key], 1u);
}

__global__ __launch_bounds__(1024) void k_scan(const unsigned* __restrict__ hist,
                                               unsigned* __restrict__ cursor) {
    __shared__ unsigned sums[1024];
    const int t = threadIdx.x;
    const int per = NBUCK / 1024;          // 32
    unsigned s = 0;
    #pragma unroll
    for (int j = 0; j < per; ++j) s += hist[t * per + j];
    sums[t] = s;
    __syncthreads();
    for (int off = 1; off < 1024; off <<= 1) {
        const unsigned add = (t >= off) ? sums[t - off] : 0u;
        __syncthreads();
        sums[t] += add;
        __syncthreads();
    }
    unsigned run = (t == 0) ? 0u : sums[t - 1];
    #pragma unroll
    for (int j = 0; j < per; ++j) {
        cursor[t * per + j] = run;
        run += hist[t * per + j];
    }
}

__global__ __launch_bounds__(256) void k_scatter(const float* __restrict__ xs,
                                                 const int* __restrict__ inds, int N,
                                                 unsigned* __restrict__ cursor,
                                                 float4* __restrict__ sorted) {
    const int i = blockIdx.x * 256 + threadIdx.x;
    if (i >= N) return;
    const float x = xs[3 * i], y = xs[3 * i + 1], z = xs[3 * i + 2];
    const unsigned tree = (unsigned)(inds[i] & 7);
    const unsigned key = bucket_key(x, y, z, tree);
    const unsigned pos = atomicAdd(&cursor[key], 1u);
    sorted[pos] = make_float4(x, y, z, __uint_as_float(((unsigned)i) | (tree << 24)));
}

// ---------------- one level, compile-time L, NO arrays anywhere ------------

template<int L>
__device__ __forceinline__ float2 level_one(const float4 p, int tree,
                                            const float* __restrict__ params) {
    constexpr float rm1 = RM1_C[L];
    constexpr int rmax = (int)rm1;

    const float px = (p.x * 0.5f + 0.5f) * rm1;
    const float py = (p.y * 0.5f + 0.5f) * rm1;
    const float pz = (p.z * 0.5f + 0.5f) * rm1;
    const float fx = floorf(px), fy = floorf(py), fz = floorf(pz);
    const float wx = px - fx, wy = py - fy, wz = pz - fz;
    const int ix = (int)fx, iy = (int)fy, iz = (int)fz;

    const int x0 = min(max(ix, 0), rmax), x1 = min(max(ix + 1, 0), rmax);
    const int y0 = min(max(iy, 0), rmax), y1 = min(max(iy + 1, 0), rmax);
    const int z0 = min(max(iz, 0), rmax), z1 = min(max(iz + 1, 0), rmax);

    const unsigned hx0 = (unsigned)x0;
    const unsigned hx1 = (unsigned)x1;
    const unsigned hy0 = (unsigned)y0 * 2654435761u;
    const unsigned hy1 = (unsigned)y1 * 2654435761u;
    const unsigned hz0 = (unsigned)z0 * 805459861u;
    const unsigned hz1 = (unsigned)z1 * 805459861u;

    const float2* __restrict__ tbl =
        (const float2*)(params + (size_t)(tree * NLEVELS + L) * (TSIZE * 2));

    const unsigned m00 = hy0 ^ hz0;
    const unsigned m01 = hy0 ^ hz1;
    const unsigned m10 = hy1 ^ hz0;
    const unsigned m11 = hy1 ^ hz1;
    const unsigned i000 = (hx0 ^ m00) & TMASK;
    const unsigned i001 = (hx0 ^ m01) & TMASK;
    const unsigned i010 = (hx0 ^ m10) & TMASK;
    const unsigned i011 = (hx0 ^ m11) & TMASK;

    float2 f0, f1, f2, f3, f4, f5, f6, f7;   // named registers only

    // x-prime is 1: if x0 even and x1==x0+1, the two x-corners are ADJACENT
    // table entries {2j,2j+1} -> one aligned float4 covers both.
    const bool pairOK = ((x0 & 1) == 0) && (x1 == x0 + 1);
    if (pairOK) {
        const float4* __restrict__ tbl4 = (const float4*)tbl;
        const float4 q00 = tbl4[i000 >> 1];
        const float4 q01 = tbl4[i001 >> 1];
        const float4 q10 = tbl4[i010 >> 1];
        const float4 q11 = tbl4[i011 >> 1];
        f0 = (i000 & 1) ? make_float2(q00.z, q00.w) : make_float2(q00.x, q00.y);
        f4 = (i000 & 1) ? make_float2(q00.x, q00.y) : make_float2(q00.z, q00.w);
        f1 = (i001 & 1) ? make_float2(q01.z, q01.w) : make_float2(q01.x, q01.y);
        f5 = (i001 & 1) ? make_float2(q01.x, q01.y) : make_float2(q01.z, q01.w);
        f2 = (i010 & 1) ? make_float2(q10.z, q10.w) : make_float2(q10.x, q10.y);
        f6 = (i010 & 1) ? make_float2(q10.x, q10.y) : make_float2(q10.z, q10.w);
        f3 = (i011 & 1) ? make_float2(q11.z, q11.w) : make_float2(q11.x, q11.y);
        f7 = (i011 & 1) ? make_float2(q11.x, q11.y) : make_float2(q11.z, q11.w);
    } else {
        const unsigned i100 = (hx1 ^ m00) & TMASK;
        const unsigned i101 = (hx1 ^ m01) & TMASK;
        const unsigned i110 = (hx1 ^ m10) & TMASK;
        const unsigned i111 = (hx1 ^ m11) & TMASK;
        f0 = tbl[i000]; f1 = tbl[i001];
        f2 = tbl[i010]; f3 = tbl[i011];
        f4 = tbl[i100]; f5 = tbl[i101];
        f6 = tbl[i110]; f7 = tbl[i111];
    }

    const float wx0 = 1.f - wx, wy0 = 1.f - wy, wz0 = 1.f - wz;
    const float w0 = wx0 * wy0 * wz0;
    const float w1 = wx0 * wy0 * wz;
    const float w2 = wx0 * wy  * wz0;
    const float w3 = wx0 * wy  * wz;
    const float w4 = wx  * wy0 * wz0;
    const float w5 = wx  * wy0 * wz;
    const float w6 = wx  * wy  * wz0;
    const float w7 = wx  * wy  * wz;

    float a0 = 0.f, a1 = 0.f;
    a0 = fmaf(w0, f0.x, a0); a1 = fmaf(w0, f0.y, a1);
    a0 = fmaf(w1, f1.x, a0); a1 = fmaf(w1, f1.y, a1);
    a0 = fmaf(w2, f2.x, a0); a1 = fmaf(w2, f2.y, a1);
    a0 = fmaf(w3, f3.x, a0); a1 = fmaf(w3, f3.y, a1);
    a0 = fmaf(w4, f4.x, a0); a1 = fmaf(w4, f4.y, a1);
    a0 = fmaf(w5, f5.x, a0); a1 = fmaf(w5, f5.y, a1);
    a0 = fmaf(w6, f6.x, a0); a1 = fmaf(w6, f6.y, a1);
    a0 = fmaf(w7, f7.x, a0); a1 = fmaf(w7, f7.y, a1);
    return make_float2(a0, a1);
}

// mixed quad: 2 coarse + 2 fine levels per thread -> coarse L1-hit FMA work
// hides fine-level L2 latency within every thread (round-7's key property)
template<int G>
__device__ __forceinline__ void quad_mixed(const float4 p, int tree,
                                           const float* __restrict__ params,
                                           float2& ra, float2& rb,
                                           float2& rc, float2& rd) {
    ra = level_one<G>(p, tree, params);        // coarse
    rc = level_one<8 + G>(p, tree, params);    // fine   (issue early)
    rb = level_one<7 - G>(p, tree, params);    // coarse
    rd = level_one<15 - G>(p, tree, params);   // fine
}

// ---------------- fused gather kernel (LDS transpose, no ws2/k_final) ------
// One block = 1024 threads = 256 points x 4 groups; group g computes levels
// {g, 7-g, 8+g, 15-g}. Results staged in LDS, then the block writes each
// point's full 128 B row as 64 B full-granule segments. XCD-contiguous
// bijective chunk map keeps each XCD on ~one tree.

__global__ __launch_bounds__(1024) void k_fuse(const float4* __restrict__ sorted,
                                               const float* __restrict__ params,
                                               float4* __restrict__ out4,
                                               int N, int nc) {
    __shared__ float2 lds[256][17];     // slot l = level l; +1 pad
    __shared__ unsigned nbuf[256];

    const int b = blockIdx.x;
    const int q = nc >> 3, r = nc & 7;
    const int j = b & 7;
    const int chunk = j * q + min(j, r) + (b >> 3);   // bijective [0,nc)

    const int pt = threadIdx.x & 255;
    const int g  = threadIdx.x >> 8;                  // wave-uniform
    const int i  = chunk * 256 + pt;

    if (i < N) {
        const float4 p = sorted[i];                   // L1 broadcast across g
        const unsigned wbits = __float_as_uint(p.w);
        const int tree = (int)(wbits >> 24);
        if (g == 0) nbuf[pt] = wbits & 0xFFFFFFu;

        float2 ra, rb, rc, rd;
        if      (g == 0) quad_mixed<0>(p, tree, params, ra, rb, rc, rd);
        else if (g == 1) quad_mixed<1>(p, tree, params, ra, rb, rc, rd);
        else if (g == 2) quad_mixed<2>(p, tree, params, ra, rb, rc, rd);
        else             quad_mixed<3>(p, tree, params, ra, rb, rc, rd);

        lds[pt][g]      = ra;
        lds[pt][7 - g]  = rb;
        lds[pt][8 + g]  = rc;
        lds[pt][15 - g] = rd;
    }
    __syncthreads();

    // write-out: thread t -> point t>>2, float4 slots (t&3) and (t&3)+4;
    // 4 consecutive lanes cover one 64 B segment -> full write granules.
    const int pt2 = threadIdx.x >> 2;
    const int q0  = threadIdx.x & 3;
    const int i2  = chunk * 256 + pt2;
    if (i2 < N) {
        const size_t n = nbuf[pt2];
        {
            const float2 e0 = lds[pt2][2 * q0];
            const float2 e1 = lds[pt2][2 * q0 + 1];
            out4[n * 8 + q0] = make_float4(e0.x, e0.y, e1.x, e1.y);
        }
        {
            const int q1 = q0 + 4;
            const float2 e0 = lds[pt2][2 * q1];
            const float2 e1 = lds[pt2][2 * q1 + 1];
            out4[n * 8 + q1] = make_float4(e0.x, e0.y, e1.x, e1.y);
        }
    }
}

// ---------------- fallback (fused one-pass) ----------------

__global__ __launch_bounds__(256) void lotd_fwd_fused(
    const float* __restrict__ xs, const float* __restrict__ params,
    const int* __restrict__ inds, float* __restrict__ out, int N)
{
    const int g = blockIdx.x * 256 + threadIdx.x;
    const int n = g >> 4;
    if (n >= N) return;
    const int l = g & 15;
    const float rm1 = RM1_TAB[l];
    const int rmax = (int)rm1;
    const float x = xs[3 * n], y = xs[3 * n + 1], z = xs[3 * n + 2];
    const int tree = inds[n];
    const float px = (x * 0.5f + 0.5f) * rm1;
    const float py = (y * 0.5f + 0.5f) * rm1;
    const float pz = (z * 0.5f + 0.5f) * rm1;
    const float fx = floorf(px), fy = floorf(py), fz = floorf(pz);
    const float wx = px - fx, wy = py - fy, wz = pz - fz;
    const int ix = (int)fx, iy = (int)fy, iz = (int)fz;
    const int x0 = min(max(ix, 0), rmax), x1 = min(max(ix + 1, 0), rmax);
    const int y0 = min(max(iy, 0), rmax), y1 = min(max(iy + 1, 0), rmax);
    const int z0 = min(max(iz, 0), rmax), z1 = min(max(iz + 1, 0), rmax);
    const unsigned hx0 = (unsigned)x0, hx1 = (unsigned)x1;
    const unsigned hy0 = (unsigned)y0 * 2654435761u, hy1 = (unsigned)y1 * 2654435761u;
    const unsigned hz0 = (unsigned)z0 * 805459861u,  hz1 = (unsigned)z1 * 805459861u;
    const float2* tbl = (const float2*)(params + (size_t)(tree * NLEVELS + l) * (TSIZE * 2));
    const float2 f000 = tbl[(hx0 ^ hy0 ^ hz0) & TMASK];
    const float2 f001 = tbl[(hx0 ^ hy0 ^ hz1) & TMASK];
    const float2 f010 = tbl[(hx0 ^ hy1 ^ hz0) & TMASK];
    const float2 f011 = tbl[(hx0 ^ hy1 ^ hz1) & TMASK];
    const float2 f100 = tbl[(hx1 ^ hy0 ^ hz0) & TMASK];
    const float2 f101 = tbl[(hx1 ^ hy0 ^ hz1) & TMASK];
    const float2 f110 = tbl[(hx1 ^ hy1 ^ hz0) & TMASK];
    const float2 f111 = tbl[(hx1 ^ hy1 ^ hz1) & TMASK];
    const float wx0 = 1.f - wx, wy0 = 1.f - wy, wz0 = 1.f - wz;
    float a0 = 0.f, a1 = 0.f;
    a0 = fmaf(wx0*wy0*wz0, f000.x, a0); a1 = fmaf(wx0*wy0*wz0, f000.y, a1);
    a0 = fmaf(wx0*wy0*wz , f001.x, a0); a1 = fmaf(wx0*wy0*wz , f001.y, a1);
    a0 = fmaf(wx0*wy *wz0, f010.x, a0); a1 = fmaf(wx0*wy *wz0, f010.y, a1);
    a0 = fmaf(wx0*wy *wz , f011.x, a0); a1 = fmaf(wx0*wy *wz , f011.y, a1);
    a0 = fmaf(wx *wy0*wz0, f100.x, a0); a1 = fmaf(wx *wy0*wz0, f100.y, a1);
    a0 = fmaf(wx *wy0*wz , f101.x, a0); a1 = fmaf(wx *wy0*wz , f101.y, a1);
    a0 = fmaf(wx *wy *wz0, f110.x, a0); a1 = fmaf(wx *wy *wz0, f110.y, a1);
    a0 = fmaf(wx *wy *wz , f111.x, a0); a1 = fmaf(wx *wy *wz , f111.y, a1);
    ((float2*)out)[(size_t)n * 16 + l] = make_float2(a0, a1);
}

extern "C" void kernel_launch(void* const* d_in, const int* in_sizes, int n_in,
                              void* d_out, int out_size, void* d_ws, size_t ws_size,
                              hipStream_t stream) {
    const float* xs     = (const float*)d_in[0];
    const float* params = (const float*)d_in[1];
    const int*   inds   = (const int*)d_in[2];
    float*       out    = (float*)d_out;

    const int N = in_sizes[0] / 3;
    const int nc = (N + 255) / 256;

    const size_t hist_bytes   = (size_t)NBUCK * 4;               // 128 KB
    const size_t head_bytes   = 2 * hist_bytes;                  // hist + cursor
    const size_t sorted_bytes = ((size_t)N * 16 + 255) & ~(size_t)255;
    const size_t need = head_bytes + sorted_bytes;

    if (ws_size < need) {
        const int total = N * NLEVELS;
        lotd_fwd_fused<<<(total + 255) / 256, 256, 0, stream>>>(xs, params, inds, out, N);
        return;
    }

    unsigned* hist   = (unsigned*)d_ws;
    unsigned* cursor = (unsigned*)((char*)d_ws + hist_bytes);
    float4*   sorted = (float4*)((char*)d_ws + head_bytes);

    hipMemsetAsync(hist, 0, hist_bytes, stream);
    k_hist<<<nc, 256, 0, stream>>>(xs, inds, N, hist);
    k_scan<<<1, 1024, 0, stream>>>(hist, cursor);
    k_scatter<<<nc, 256, 0, stream>>>(xs, inds, N, cursor, sorted);

    k_fuse<<<nc, 1024, 0, stream>>>(sorted, params, (float4*)out, N, nc);
}

// Round 13
// 846.704 us; speedup vs baseline: 1.1847x; 1.0017x over previous
//
#include <hip/hip_runtime.h>

#define NLEVELS 16
#define TSIZE 131072
#define TMASK (TSIZE - 1)
#define NBUCK 32768           // 8 trees x 4096 morton cells (4 bits/dim)

typedef float f32x4 __attribute__((ext_vector_type(4)));

__device__ __constant__ float RM1_TAB[16] = {
    15.f, 21.f, 29.f, 40.f, 54.f, 74.f, 101.f, 138.f,
    187.f, 255.f, 347.f, 471.f, 641.f, 871.f, 1183.f, 1607.f
};

constexpr float RM1_C[16] = {
    15.f, 21.f, 29.f, 40.f, 54.f, 74.f, 101.f, 138.f,
    187.f, 255.f, 347.f, 471.f, 641.f, 871.f, 1183.f, 1607.f
};

__device__ __forceinline__ unsigned spread4(unsigned v) {
    v = (v | (v << 4)) & 0x0C3u;
    v = (v | (v << 2)) & 0x249u;
    return v;
}

__device__ __forceinline__ unsigned bucket_key(float x, float y, float z, unsigned tree) {
    const int cx = min(max((int)((x * 0.5f + 0.5f) * 16.f), 0), 15);
    const int cy = min(max((int)((y * 0.5f + 0.5f) * 16.f), 0), 15);
    const int cz = min(max((int)((z * 0.5f + 0.5f) * 16.f), 0), 15);
    const unsigned m = spread4((unsigned)cx) | (spread4((unsigned)cy) << 1)
                     | (spread4((unsigned)cz) << 2);
    return (tree << 12) | m;
}

// ---------------- counting sort by (tree, morton12) ----------------

__global__ __launch_bounds__(256) void k_hist(const float* __restrict__ xs,
                                              const int* __restrict__ inds, int N,
                                              unsigned* __restrict__ hist) {
    const int i = blockIdx.x * 256 + threadIdx.x;
    if (i >= N) return;
    const unsigned key = bucket_key(xs[3 * i], xs[3 * i + 1], xs[3 * i + 2],
                                    (unsigned)(inds[i] & 7));
    atomicAdd(&hist[key], 1u);
}

__global__ __launch_bounds__(1024) void k_scan(const unsigned* __restrict__ hist,
                                               unsigned* __restrict__ cursor) {
    __shared__ unsigned sums[1024];
    const int t = threadIdx.x;
    const int per = NBUCK / 1024;          // 32
    unsigned s = 0;
    #pragma unroll
    for (int j = 0; j < per; ++j) s += hist[t * per + j];
    sums[t] = s;
    __syncthreads();
    for (int off = 1; off < 1024; off <<= 1) {
        const unsigned add = (t >= off) ? sums[t - off] : 0u;
        __syncthreads();
        sums[t] += add;
        __syncthreads();
    }
    unsigned run = (t == 0) ? 0u : sums[t - 1];
    #pragma unroll
    for (int j = 0; j < per; ++j) {
        cursor[t * per + j] = run;
        run += hist[t * per + j];
    }
}

__global__ __launch_bounds__(256) void k_scatter(const float* __restrict__ xs,
                                                 const int* __restrict__ inds, int N,
                                                 unsigned* __restrict__ cursor,
                                                 float4* __restrict__ sorted) {
    const int i = blockIdx.x * 256 + threadIdx.x;
    if (i >= N) return;
    const float x = xs[3 * i], y = xs[3 * i + 1], z = xs[3 * i + 2];
    const unsigned tree = (unsigned)(inds[i] & 7);
    const unsigned key = bucket_key(x, y, z, tree);
    const unsigned pos = atomicAdd(&cursor[key], 1u);
    sorted[pos] = make_float4(x, y, z, __uint_as_float(((unsigned)i) | (tree << 24)));
}

// ---------------- one level, compile-time L, NO arrays anywhere ------------

template<int L>
__device__ __forceinline__ float2 level_one(const float4 p, int tree,
                                            const float* __restrict__ params) {
    constexpr float rm1 = RM1_C[L];
    constexpr int rmax = (int)rm1;

    const float px = (p.x * 0.5f + 0.5f) * rm1;
    const float py = (p.y * 0.5f + 0.5f) * rm1;
    const float pz = (p.z * 0.5f + 0.5f) * rm1;
    const float fx = floorf(px), fy = floorf(py), fz = floorf(pz);
    const float wx = px - fx, wy = py - fy, wz = pz - fz;
    const int ix = (int)fx, iy = (int)fy, iz = (int)fz;

    const int x0 = min(max(ix, 0), rmax), x1 = min(max(ix + 1, 0), rmax);
    const int y0 = min(max(iy, 0), rmax), y1 = min(max(iy + 1, 0), rmax);
    const int z0 = min(max(iz, 0), rmax), z1 = min(max(iz + 1, 0), rmax);

    const unsigned hx0 = (unsigned)x0;
    const unsigned hx1 = (unsigned)x1;
    const unsigned hy0 = (unsigned)y0 * 2654435761u;
    const unsigned hy1 = (unsigned)y1 * 2654435761u;
    const unsigned hz0 = (unsigned)z0 * 805459861u;
    const unsigned hz1 = (unsigned)z1 * 805459861u;

    const float2* __restrict__ tbl =
        (const float2*)(params + (size_t)(tree * NLEVELS + L) * (TSIZE * 2));

    const unsigned m00 = hy0 ^ hz0;
    const unsigned m01 = hy0 ^ hz1;
    const unsigned m10 = hy1 ^ hz0;
    const unsigned m11 = hy1 ^ hz1;
    const unsigned i000 = (hx0 ^ m00) & TMASK;
    const unsigned i001 = (hx0 ^ m01) & TMASK;
    const unsigned i010 = (hx0 ^ m10) & TMASK;
    const unsigned i011 = (hx0 ^ m11) & TMASK;

    float2 f0, f1, f2, f3, f4, f5, f6, f7;   // named registers only

    // x-prime is 1: if x0 even and x1==x0+1, the two x-corners are ADJACENT
    // table entries {2j,2j+1} -> one aligned float4 covers both.
    const bool pairOK = ((x0 & 1) == 0) && (x1 == x0 + 1);
    if (pairOK) {
        const float4* __restrict__ tbl4 = (const float4*)tbl;
        const float4 q00 = tbl4[i000 >> 1];
        const float4 q01 = tbl4[i001 >> 1];
        const float4 q10 = tbl4[i010 >> 1];
        const float4 q11 = tbl4[i011 >> 1];
        f0 = (i000 & 1) ? make_float2(q00.z, q00.w) : make_float2(q00.x, q00.y);
        f4 = (i000 & 1) ? make_float2(q00.x, q00.y) : make_float2(q00.z, q00.w);
        f1 = (i001 & 1) ? make_float2(q01.z, q01.w) : make_float2(q01.x, q01.y);
        f5 = (i001 & 1) ? make_float2(q01.x, q01.y) : make_float2(q01.z, q01.w);
        f2 = (i010 & 1) ? make_float2(q10.z, q10.w) : make_float2(q10.x, q10.y);
        f6 = (i010 & 1) ? make_float2(q10.x, q10.y) : make_float2(q10.z, q10.w);
        f3 = (i011 & 1) ? make_float2(q11.z, q11.w) : make_float2(q11.x, q11.y);
        f7 = (i011 & 1) ? make_float2(q11.x, q11.y) : make_float2(q11.z, q11.w);
    } else {
        const unsigned i100 = (hx1 ^ m00) & TMASK;
        const unsigned i101 = (hx1 ^ m01) & TMASK;
        const unsigned i110 = (hx1 ^ m10) & TMASK;
        const unsigned i111 = (hx1 ^ m11) & TMASK;
        f0 = tbl[i000]; f1 = tbl[i001];
        f2 = tbl[i010]; f3 = tbl[i011];
        f4 = tbl[i100]; f5 = tbl[i101];
        f6 = tbl[i110]; f7 = tbl[i111];
    }

    const float wx0 = 1.f - wx, wy0 = 1.f - wy, wz0 = 1.f - wz;
    const float w0 = wx0 * wy0 * wz0;
    const float w1 = wx0 * wy0 * wz;
    const float w2 = wx0 * wy  * wz0;
    const float w3 = wx0 * wy  * wz;
    const float w4 = wx  * wy0 * wz0;
    const float w5 = wx  * wy0 * wz;
    const float w6 = wx  * wy  * wz0;
    const float w7 = wx  * wy  * wz;

    float a0 = 0.f, a1 = 0.f;
    a0 = fmaf(w0, f0.x, a0); a1 = fmaf(w0, f0.y, a1);
    a0 = fmaf(w1, f1.x, a0); a1 = fmaf(w1, f1.y, a1);
    a0 = fmaf(w2, f2.x, a0); a1 = fmaf(w2, f2.y, a1);
    a0 = fmaf(w3, f3.x, a0); a1 = fmaf(w3, f3.y, a1);
    a0 = fmaf(w4, f4.x, a0); a1 = fmaf(w4, f4.y, a1);
    a0 = fmaf(w5, f5.x, a0); a1 = fmaf(w5, f5.y, a1);
    a0 = fmaf(w6, f6.x, a0); a1 = fmaf(w6, f6.y, a1);
    a0 = fmaf(w7, f7.x, a0); a1 = fmaf(w7, f7.y, a1);
    return make_float2(a0, a1);
}

// mixed quad: 2 coarse + 2 fine levels per thread -> coarse L1-hit FMA work
// hides fine-level L2/L3 latency within every thread
template<int G>
__device__ __forceinline__ void quad_mixed(const float4 p, int tree,
                                           const float* __restrict__ params,
                                           float2& ra, float2& rb,
                                           float2& rc, float2& rd) {
    ra = level_one<G>(p, tree, params);        // coarse
    rc = level_one<8 + G>(p, tree, params);    // fine   (issue early)
    rb = level_one<7 - G>(p, tree, params);    // coarse
    rd = level_one<15 - G>(p, tree, params);   // fine
}

// ---------------- fused gather kernel (LDS transpose, no ws2/k_final) ------
// One block = 512 threads = 128 points x 4 groups (8 waves/block -> up to
// 4 blocks/CU at 60 VGPR = 32 waves, vs 1024-thread version's 2-block
// granularity that measured 46% occupancy). Group g computes levels
// {g, 7-g, 8+g, 15-g}; results staged in LDS; block writes each point's full
// 128 B row as 64 B segments with NT stores (no L2 pollution of the tables).
// XCD-contiguous bijective chunk map keeps each XCD on ~one tree.

__global__ __launch_bounds__(512) void k_fuse(const float4* __restrict__ sorted,
                                              const float* __restrict__ params,
                                              float4* __restrict__ out4,
                                              int N, int nc) {
    __shared__ float2 lds[128][17];     // slot l = level l; +1 pad
    __shared__ unsigned nbuf[128];

    const int b = blockIdx.x;
    const int q = nc >> 3, r = nc & 7;
    const int j = b & 7;
    const int chunk = j * q + min(j, r) + (b >> 3);   // bijective [0,nc)

    const int pt = threadIdx.x & 127;
    const int g  = threadIdx.x >> 7;                  // wave-uniform
    const int i  = chunk * 128 + pt;

    if (i < N) {
        const f32x4 pv = __builtin_nontemporal_load((const f32x4*)&sorted[i]);
        const float4 p = *(const float4*)&pv;         // L1 broadcast across g
        const unsigned wbits = __float_as_uint(p.w);
        const int tree = (int)(wbits >> 24);
        if (g == 0) nbuf[pt] = wbits & 0xFFFFFFu;

        float2 ra, rb, rc, rd;
        if      (g == 0) quad_mixed<0>(p, tree, params, ra, rb, rc, rd);
        else if (g == 1) quad_mixed<1>(p, tree, params, ra, rb, rc, rd);
        else if (g == 2) quad_mixed<2>(p, tree, params, ra, rb, rc, rd);
        else             quad_mixed<3>(p, tree, params, ra, rb, rc, rd);

        lds[pt][g]      = ra;
        lds[pt][7 - g]  = rb;
        lds[pt][8 + g]  = rc;
        lds[pt][15 - g] = rd;
    }
    __syncthreads();

    // write-out: thread t -> point t>>2, float4 slots (t&3) and (t&3)+4;
    // 4 consecutive lanes cover one 64 B segment -> full write granules.
    const int pt2 = threadIdx.x >> 2;
    const int q0  = threadIdx.x & 3;
    const int i2  = chunk * 128 + pt2;
    if (i2 < N) {
        const size_t n = nbuf[pt2];
        {
            const float2 e0 = lds[pt2][2 * q0];
            const float2 e1 = lds[pt2][2 * q0 + 1];
            const float4 o = make_float4(e0.x, e0.y, e1.x, e1.y);
            __builtin_nontemporal_store(*(const f32x4*)&o, (f32x4*)&out4[n * 8 + q0]);
        }
        {
            const int q1 = q0 + 4;
            const float2 e0 = lds[pt2][2 * q1];
            const float2 e1 = lds[pt2][2 * q1 + 1];
            const float4 o = make_float4(e0.x, e0.y, e1.x, e1.y);
            __builtin_nontemporal_store(*(const f32x4*)&o, (f32x4*)&out4[n * 8 + q1]);
        }
    }
}

// ---------------- fallback (fused one-pass) ----------------

__global__ __launch_bounds__(256) void lotd_fwd_fused(
    const float* __restrict__ xs, const float* __restrict__ params,
    const int* __restrict__ inds, float* __restrict__ out, int N)
{
    const int g = blockIdx.x * 256 + threadIdx.x;
    const int n = g >> 4;
    if (n >= N) return;
    const int l = g & 15;
    const float rm1 = RM1_TAB[l];
    const int rmax = (int)rm1;
    const float x = xs[3 * n], y = xs[3 * n + 1], z = xs[3 * n + 2];
    const int tree = inds[n];
    const float px = (x * 0.5f + 0.5f) * rm1;
    const float py = (y * 0.5f + 0.5f) * rm1;
    const float pz = (z * 0.5f + 0.5f) * rm1;
    const float fx = floorf(px), fy = floorf(py), fz = floorf(pz);
    const float wx = px - fx, wy = py - fy, wz = pz - fz;
    const int ix = (int)fx, iy = (int)fy, iz = (int)fz;
    const int x0 = min(max(ix, 0), rmax), x1 = min(max(ix + 1, 0), rmax);
    const int y0 = min(max(iy, 0), rmax), y1 = min(max(iy + 1, 0), rmax);
    const int z0 = min(max(iz, 0), rmax), z1 = min(max(iz + 1, 0), rmax);
    const unsigned hx0 = (unsigned)x0, hx1 = (unsigned)x1;
    const unsigned hy0 = (unsigned)y0 * 2654435761u, hy1 = (unsigned)y1 * 2654435761u;
    const unsigned hz0 = (unsigned)z0 * 805459861u,  hz1 = (unsigned)z1 * 805459861u;
    const float2* tbl = (const float2*)(params + (size_t)(tree * NLEVELS + l) * (TSIZE * 2));
    const float2 f000 = tbl[(hx0 ^ hy0 ^ hz0) & TMASK];
    const float2 f001 = tbl[(hx0 ^ hy0 ^ hz1) & TMASK];
    const float2 f010 = tbl[(hx0 ^ hy1 ^ hz0) & TMASK];
    const float2 f011 = tbl[(hx0 ^ hy1 ^ hz1) & TMASK];
    const float2 f100 = tbl[(hx1 ^ hy0 ^ hz0) & TMASK];
    const float2 f101 = tbl[(hx1 ^ hy0 ^ hz1) & TMASK];
    const float2 f110 = tbl[(hx1 ^ hy1 ^ hz0) & TMASK];
    const float2 f111 = tbl[(hx1 ^ hy1 ^ hz1) & TMASK];
    const float wx0 = 1.f - wx, wy0 = 1.f - wy, wz0 = 1.f - wz;
    float a0 = 0.f, a1 = 0.f;
    a0 = fmaf(wx0*wy0*wz0, f000.x, a0); a1 = fmaf(wx0*wy0*wz0, f000.y, a1);
    a0 = fmaf(wx0*wy0*wz , f001.x, a0); a1 = fmaf(wx0*wy0*wz , f001.y, a1);
    a0 = fmaf(wx0*wy *wz0, f010.x, a0); a1 = fmaf(wx0*wy *wz0, f010.y, a1);
    a0 = fmaf(wx0*wy *wz , f011.x, a0); a1 = fmaf(wx0*wy *wz , f011.y, a1);
    a0 = fmaf(wx *wy0*wz0, f100.x, a0); a1 = fmaf(wx *wy0*wz0, f100.y, a1);
    a0 = fmaf(wx *wy0*wz , f101.x, a0); a1 = fmaf(wx *wy0*wz , f101.y, a1);
    a0 = fmaf(wx *wy *wz0, f110.x, a0); a1 = fmaf(wx *wy *wz0, f110.y, a1);
    a0 = fmaf(wx *wy *wz , f111.x, a0); a1 = fmaf(wx *wy *wz , f111.y, a1);
    ((float2*)out)[(size_t)n * 16 + l] = make_float2(a0, a1);
}

extern "C" void kernel_launch(void* const* d_in, const int* in_sizes, int n_in,
                              void* d_out, int out_size, void* d_ws, size_t ws_size,
                              hipStream_t stream) {
    const float* xs     = (const float*)d_in[0];
    const float* params = (const float*)d_in[1];
    const int*   inds   = (const int*)d_in[2];
    float*       out    = (float*)d_out;

    const int N = in_sizes[0] / 3;
    const int nc256 = (N + 255) / 256;       // for sort kernels
    const int nc128 = (N + 127) / 128;       // for k_fuse (128-pt chunks)

    const size_t hist_bytes   = (size_t)NBUCK * 4;               // 128 KB
    const size_t head_bytes   = 2 * hist_bytes;                  // hist + cursor
    const size_t sorted_bytes = ((size_t)N * 16 + 255) & ~(size_t)255;
    const size_t need = head_bytes + sorted_bytes;

    if (ws_size < need) {
        const int total = N * NLEVELS;
        lotd_fwd_fused<<<(total + 255) / 256, 256, 0, stream>>>(xs, params, inds, out, N);
        return;
    }

    unsigned* hist   = (unsigned*)d_ws;
    unsigned* cursor = (unsigned*)((char*)d_ws + hist_bytes);
    float4*   sorted = (float4*)((char*)d_ws + head_bytes);

    hipMemsetAsync(hist, 0, hist_bytes, stream);
    k_hist<<<nc256, 256, 0, stream>>>(xs, inds, N, hist);
    k_scan<<<1, 1024, 0, stream>>>(hist, cursor);
    k_scatter<<<nc256, 256, 0, stream>>>(xs, inds, N, cursor, sorted);

    k_fuse<<<nc128, 512, 0, stream>>>(sorted, params, (float4*)out, N, nc128);
}

// Round 14
// 764.328 us; speedup vs baseline: 1.3124x; 1.1078x over previous
//
#include <hip/hip_runtime.h>

#define NLEVELS 16
#define TSIZE 131072
#define TMASK (TSIZE - 1)
#define NBUCK 32768           // 8 trees x 4096 morton cells (4 bits/dim)

typedef float f32x4 __attribute__((ext_vector_type(4)));

__device__ __constant__ float RM1_TAB[16] = {
    15.f, 21.f, 29.f, 40.f, 54.f, 74.f, 101.f, 138.f,
    187.f, 255.f, 347.f, 471.f, 641.f, 871.f, 1183.f, 1607.f
};

constexpr float RM1_C[16] = {
    15.f, 21.f, 29.f, 40.f, 54.f, 74.f, 101.f, 138.f,
    187.f, 255.f, 347.f, 471.f, 641.f, 871.f, 1183.f, 1607.f
};

__device__ __forceinline__ unsigned spread4(unsigned v) {
    v = (v | (v << 4)) & 0x0C3u;
    v = (v | (v << 2)) & 0x249u;
    return v;
}

__device__ __forceinline__ unsigned bucket_key(float x, float y, float z, unsigned tree) {
    const int cx = min(max((int)((x * 0.5f + 0.5f) * 16.f), 0), 15);
    const int cy = min(max((int)((y * 0.5f + 0.5f) * 16.f), 0), 15);
    const int cz = min(max((int)((z * 0.5f + 0.5f) * 16.f), 0), 15);
    const unsigned m = spread4((unsigned)cx) | (spread4((unsigned)cy) << 1)
                     | (spread4((unsigned)cz) << 2);
    return (tree << 12) | m;
}

// ---------------- counting sort by (tree, morton12) ----------------

__global__ __launch_bounds__(256) void k_hist(const float* __restrict__ xs,
                                              const int* __restrict__ inds, int N,
                                              unsigned* __restrict__ hist) {
    const int i = blockIdx.x * 256 + threadIdx.x;
    if (i >= N) return;
    const unsigned key = bucket_key(xs[3 * i], xs[3 * i + 1], xs[3 * i + 2],
                                    (unsigned)(inds[i] & 7));
    atomicAdd(&hist[key], 1u);
}

__global__ __launch_bounds__(1024) void k_scan(const unsigned* __restrict__ hist,
                                               unsigned* __restrict__ cursor) {
    __shared__ unsigned sums[1024];
    const int t = threadIdx.x;
    const int per = NBUCK / 1024;          // 32
    unsigned s = 0;
    #pragma unroll
    for (int j = 0; j < per; ++j) s += hist[t * per + j];
    sums[t] = s;
    __syncthreads();
    for (int off = 1; off < 1024; off <<= 1) {
        const unsigned add = (t >= off) ? sums[t - off] : 0u;
        __syncthreads();
        sums[t] += add;
        __syncthreads();
    }
    unsigned run = (t == 0) ? 0u : sums[t - 1];
    #pragma unroll
    for (int j = 0; j < per; ++j) {
        cursor[t * per + j] = run;
        run += hist[t * per + j];
    }
}

__global__ __launch_bounds__(256) void k_scatter(const float* __restrict__ xs,
                                                 const int* __restrict__ inds, int N,
                                                 unsigned* __restrict__ cursor,
                                                 float4* __restrict__ sorted) {
    const int i = blockIdx.x * 256 + threadIdx.x;
    if (i >= N) return;
    const float x = xs[3 * i], y = xs[3 * i + 1], z = xs[3 * i + 2];
    const unsigned tree = (unsigned)(inds[i] & 7);
    const unsigned key = bucket_key(x, y, z, tree);
    const unsigned pos = atomicAdd(&cursor[key], 1u);
    sorted[pos] = make_float4(x, y, z, __uint_as_float(((unsigned)i) | (tree << 24)));
}

// ---------------- one level, compile-time L, NO arrays anywhere ------------

template<int L>
__device__ __forceinline__ float2 level_one(const float4 p, int tree,
                                            const float* __restrict__ params) {
    constexpr float rm1 = RM1_C[L];
    constexpr int rmax = (int)rm1;

    const float px = (p.x * 0.5f + 0.5f) * rm1;
    const float py = (p.y * 0.5f + 0.5f) * rm1;
    const float pz = (p.z * 0.5f + 0.5f) * rm1;
    const float fx = floorf(px), fy = floorf(py), fz = floorf(pz);
    const float wx = px - fx, wy = py - fy, wz = pz - fz;
    const int ix = (int)fx, iy = (int)fy, iz = (int)fz;

    const int x0 = min(max(ix, 0), rmax), x1 = min(max(ix + 1, 0), rmax);
    const int y0 = min(max(iy, 0), rmax), y1 = min(max(iy + 1, 0), rmax);
    const int z0 = min(max(iz, 0), rmax), z1 = min(max(iz + 1, 0), rmax);

    const unsigned hx0 = (unsigned)x0;
    const unsigned hx1 = (unsigned)x1;
    const unsigned hy0 = (unsigned)y0 * 2654435761u;
    const unsigned hy1 = (unsigned)y1 * 2654435761u;
    const unsigned hz0 = (unsigned)z0 * 805459861u;
    const unsigned hz1 = (unsigned)z1 * 805459861u;

    const float2* __restrict__ tbl =
        (const float2*)(params + (size_t)(tree * NLEVELS + L) * (TSIZE * 2));

    const unsigned m00 = hy0 ^ hz0;
    const unsigned m01 = hy0 ^ hz1;
    const unsigned m10 = hy1 ^ hz0;
    const unsigned m11 = hy1 ^ hz1;
    const unsigned i000 = (hx0 ^ m00) & TMASK;
    const unsigned i001 = (hx0 ^ m01) & TMASK;
    const unsigned i010 = (hx0 ^ m10) & TMASK;
    const unsigned i011 = (hx0 ^ m11) & TMASK;

    float2 f0, f1, f2, f3, f4, f5, f6, f7;   // named registers only

    // x-prime is 1: if x0 even and x1==x0+1, the two x-corners are ADJACENT
    // table entries {2j,2j+1} -> one aligned float4 covers both.
    const bool pairOK = ((x0 & 1) == 0) && (x1 == x0 + 1);
    if (pairOK) {
        const float4* __restrict__ tbl4 = (const float4*)tbl;
        const float4 q00 = tbl4[i000 >> 1];
        const float4 q01 = tbl4[i001 >> 1];
        const float4 q10 = tbl4[i010 >> 1];
        const float4 q11 = tbl4[i011 >> 1];
        f0 = (i000 & 1) ? make_float2(q00.z, q00.w) : make_float2(q00.x, q00.y);
        f4 = (i000 & 1) ? make_float2(q00.x, q00.y) : make_float2(q00.z, q00.w);
        f1 = (i001 & 1) ? make_float2(q01.z, q01.w) : make_float2(q01.x, q01.y);
        f5 = (i001 & 1) ? make_float2(q01.x, q01.y) : make_float2(q01.z, q01.w);
        f2 = (i010 & 1) ? make_float2(q10.z, q10.w) : make_float2(q10.x, q10.y);
        f6 = (i010 & 1) ? make_float2(q10.x, q10.y) : make_float2(q10.z, q10.w);
        f3 = (i011 & 1) ? make_float2(q11.z, q11.w) : make_float2(q11.x, q11.y);
        f7 = (i011 & 1) ? make_float2(q11.x, q11.y) : make_float2(q11.z, q11.w);
    } else {
        const unsigned i100 = (hx1 ^ m00) & TMASK;
        const unsigned i101 = (hx1 ^ m01) & TMASK;
        const unsigned i110 = (hx1 ^ m10) & TMASK;
        const unsigned i111 = (hx1 ^ m11) & TMASK;
        f0 = tbl[i000]; f1 = tbl[i001];
        f2 = tbl[i010]; f3 = tbl[i011];
        f4 = tbl[i100]; f5 = tbl[i101];
        f6 = tbl[i110]; f7 = tbl[i111];
    }

    const float wx0 = 1.f - wx, wy0 = 1.f - wy, wz0 = 1.f - wz;
    const float w0 = wx0 * wy0 * wz0;
    const float w1 = wx0 * wy0 * wz;
    const float w2 = wx0 * wy  * wz0;
    const float w3 = wx0 * wy  * wz;
    const float w4 = wx  * wy0 * wz0;
    const float w5 = wx  * wy0 * wz;
    const float w6 = wx  * wy  * wz0;
    const float w7 = wx  * wy  * wz;

    float a0 = 0.f, a1 = 0.f;
    a0 = fmaf(w0, f0.x, a0); a1 = fmaf(w0, f0.y, a1);
    a0 = fmaf(w1, f1.x, a0); a1 = fmaf(w1, f1.y, a1);
    a0 = fmaf(w2, f2.x, a0); a1 = fmaf(w2, f2.y, a1);
    a0 = fmaf(w3, f3.x, a0); a1 = fmaf(w3, f3.y, a1);
    a0 = fmaf(w4, f4.x, a0); a1 = fmaf(w4, f4.y, a1);
    a0 = fmaf(w5, f5.x, a0); a1 = fmaf(w5, f5.y, a1);
    a0 = fmaf(w6, f6.x, a0); a1 = fmaf(w6, f6.y, a1);
    a0 = fmaf(w7, f7.x, a0); a1 = fmaf(w7, f7.y, a1);
    return make_float2(a0, a1);
}

// one balanced level pair (V, 15-V), both levels fully inlined with named
// registers and compile-time tables -> the scheduler can issue BOTH levels'
// gathers before any FMA (intra-thread MLP x2)
template<int V>
__device__ __forceinline__ float4 pair_compute(const float4 p, int tree,
                                               const float* __restrict__ params) {
    const float2 rA = level_one<V>(p, tree, params);
    const float2 rB = level_one<15 - V>(p, tree, params);
    return make_float4(rA.x, rA.y, rB.x, rB.y);
}

// ---------------- main gather kernel (round-7 structure) ----------------
// Static, exactly-balanced mapping: j = b&7 (XCD via round-robin dispatch),
// chunk = b>>3 walks morton-sorted points, band = chunk/band_sz, level pair
// v = (j+band)&7 -> levels (v, 15-v). Every XCD executes every level pair on
// exactly 1/8 of the chunks -> equal per-XCD totals; instantaneous window
// keeps one pair + one tree (2 MB, L2-resident) per XCD.

__global__ __launch_bounds__(256) void k_main(const float4* __restrict__ sorted,
                                              const float* __restrict__ params,
                                              float4* __restrict__ ws2,   // [8][nc*256]
                                              float4* __restrict__ out4,  // direct mode
                                              int N, int nc, int band_sz, int direct) {
    const int b = blockIdx.x;
    const int j = b & 7;
    const int chunk = b >> 3;
    const int band = chunk / band_sz;
    const int v = (j + band) & 7;
    const int i = chunk * 256 + (int)threadIdx.x;
    if (i >= N) return;

    const float4 p = sorted[i];
    const unsigned wbits = __float_as_uint(p.w);
    const int n = (int)(wbits & 0xFFFFFFu);
    const int tree = (int)(wbits >> 24);

    float4 o;
    switch (v) {
        case 0: o = pair_compute<0>(p, tree, params); break;
        case 1: o = pair_compute<1>(p, tree, params); break;
        case 2: o = pair_compute<2>(p, tree, params); break;
        case 3: o = pair_compute<3>(p, tree, params); break;
        case 4: o = pair_compute<4>(p, tree, params); break;
        case 5: o = pair_compute<5>(p, tree, params); break;
        case 6: o = pair_compute<6>(p, tree, params); break;
        default: o = pair_compute<7>(p, tree, params); break;
    }

    if (direct) {
        ((float2*)out4)[(size_t)n * 16 + v]        = make_float2(o.x, o.y);
        ((float2*)out4)[(size_t)n * 16 + (15 - v)] = make_float2(o.z, o.w);
    } else {
        // stream v: {level v: (x,y), level 15-v: (z,w)}; coalesced NT store
        const size_t stride = (size_t)nc * 256;
        __builtin_nontemporal_store(*(const f32x4*)&o,
                                    (f32x4*)&ws2[(size_t)v * stride + i]);
    }
}

// ---------------- un-permute: sorted rows -> out rows ----------------
// stream v carries levels (v, 15-v); reassemble the 32-float row in registers.

__global__ __launch_bounds__(256) void k_final(const float4* __restrict__ sorted,
                                               const float4* __restrict__ ws2,
                                               float4* __restrict__ out4,
                                               int N, int nc) {
    const int i = blockIdx.x * 256 + threadIdx.x;
    if (i >= N) return;
    const unsigned wbits = __float_as_uint(sorted[i].w);
    const int n = (int)(wbits & 0xFFFFFFu);
    const size_t stride = (size_t)nc * 256;

    float4 q[8];
    #pragma unroll
    for (int j = 0; j < 8; ++j) {
        f32x4 v = __builtin_nontemporal_load((const f32x4*)&ws2[(size_t)j * stride + i]);
        q[j] = *(const float4*)&v;
    }
    // float2 slot l: l<8 -> (q[l].x, q[l].y); l>=8 -> (q[15-l].z, q[15-l].w)
    #pragma unroll
    for (int kk = 0; kk < 8; ++kk) {
        float4 o;
        if (kk < 4) {
            o = make_float4(q[2 * kk].x, q[2 * kk].y, q[2 * kk + 1].x, q[2 * kk + 1].y);
        } else {
            o = make_float4(q[15 - 2 * kk].z, q[15 - 2 * kk].w,
                            q[14 - 2 * kk].z, q[14 - 2 * kk].w);
        }
        out4[(size_t)n * 8 + kk] = o;
    }
}

// ---------------- fallback (fused one-pass) ----------------

__global__ __launch_bounds__(256) void lotd_fwd_fused(
    const float* __restrict__ xs, const float* __restrict__ params,
    const int* __restrict__ inds, float* __restrict__ out, int N)
{
    const int g = blockIdx.x * 256 + threadIdx.x;
    const int n = g >> 4;
    if (n >= N) return;
    const int l = g & 15;
    const float rm1 = RM1_TAB[l];
    const int rmax = (int)rm1;
    const float x = xs[3 * n], y = xs[3 * n + 1], z = xs[3 * n + 2];
    const int tree = inds[n];
    const float px = (x * 0.5f + 0.5f) * rm1;
    const float py = (y * 0.5f + 0.5f) * rm1;
    const float pz = (z * 0.5f + 0.5f) * rm1;
    const float fx = floorf(px), fy = floorf(py), fz = floorf(pz);
    const float wx = px - fx, wy = py - fy, wz = pz - fz;
    const int ix = (int)fx, iy = (int)fy, iz = (int)fz;
    const int x0 = min(max(ix, 0), rmax), x1 = min(max(ix + 1, 0), rmax);
    const int y0 = min(max(iy, 0), rmax), y1 = min(max(iy + 1, 0), rmax);
    const int z0 = min(max(iz, 0), rmax), z1 = min(max(iz + 1, 0), rmax);
    const unsigned hx0 = (unsigned)x0, hx1 = (unsigned)x1;
    const unsigned hy0 = (unsigned)y0 * 2654435761u, hy1 = (unsigned)y1 * 2654435761u;
    const unsigned hz0 = (unsigned)z0 * 805459861u,  hz1 = (unsigned)z1 * 805459861u;
    const float2* tbl = (const float2*)(params + (size_t)(tree * NLEVELS + l) * (TSIZE * 2));
    const float2 f000 = tbl[(hx0 ^ hy0 ^ hz0) & TMASK];
    const float2 f001 = tbl[(hx0 ^ hy0 ^ hz1) & TMASK];
    const float2 f010 = tbl[(hx0 ^ hy1 ^ hz0) & TMASK];
    const float2 f011 = tbl[(hx0 ^ hy1 ^ hz1) & TMASK];
    const float2 f100 = tbl[(hx1 ^ hy0 ^ hz0) & TMASK];
    const float2 f101 = tbl[(hx1 ^ hy0 ^ hz1) & TMASK];
    const float2 f110 = tbl[(hx1 ^ hy1 ^ hz0) & TMASK];
    const float2 f111 = tbl[(hx1 ^ hy1 ^ hz1) & TMASK];
    const float wx0 = 1.f - wx, wy0 = 1.f - wy, wz0 = 1.f - wz;
    float a0 = 0.f, a1 = 0.f;
    a0 = fmaf(wx0*wy0*wz0, f000.x, a0); a1 = fmaf(wx0*wy0*wz0, f000.y, a1);
    a0 = fmaf(wx0*wy0*wz , f001.x, a0); a1 = fmaf(wx0*wy0*wz , f001.y, a1);
    a0 = fmaf(wx0*wy *wz0, f010.x, a0); a1 = fmaf(wx0*wy *wz0, f010.y, a1);
    a0 = fmaf(wx0*wy *wz , f011.x, a0); a1 = fmaf(wx0*wy *wz , f011.y, a1);
    a0 = fmaf(wx *wy0*wz0, f100.x, a0); a1 = fmaf(wx *wy0*wz0, f100.y, a1);
    a0 = fmaf(wx *wy0*wz , f101.x, a0); a1 = fmaf(wx *wy0*wz , f101.y, a1);
    a0 = fmaf(wx *wy *wz0, f110.x, a0); a1 = fmaf(wx *wy *wz0, f110.y, a1);
    a0 = fmaf(wx *wy *wz , f111.x, a0); a1 = fmaf(wx *wy *wz , f111.y, a1);
    ((float2*)out)[(size_t)n * 16 + l] = make_float2(a0, a1);
}

extern "C" void kernel_launch(void* const* d_in, const int* in_sizes, int n_in,
                              void* d_out, int out_size, void* d_ws, size_t ws_size,
                              hipStream_t stream) {
    const float* xs     = (const float*)d_in[0];
    const float* params = (const float*)d_in[1];
    const int*   inds   = (const int*)d_in[2];
    float*       out    = (float*)d_out;

    const int N = in_sizes[0] / 3;
    const int nc = (N + 255) / 256;
    const int band_sz = (nc + 7) / 8;

    const size_t hist_bytes   = (size_t)NBUCK * 4;               // 128 KB
    const size_t head_bytes   = 2 * hist_bytes;                  // hist + cursor
    const size_t sorted_bytes = ((size_t)N * 16 + 255) & ~(size_t)255;
    const size_t ws2_bytes    = (size_t)nc * 256 * 8 * 16;
    const size_t need_B = head_bytes + sorted_bytes;
    const size_t need_A = need_B + ws2_bytes;

    if (ws_size < need_B) {
        const int total = N * NLEVELS;
        lotd_fwd_fused<<<(total + 255) / 256, 256, 0, stream>>>(xs, params, inds, out, N);
        return;
    }

    unsigned* hist   = (unsigned*)d_ws;
    unsigned* cursor = (unsigned*)((char*)d_ws + hist_bytes);
    float4*   sorted = (float4*)((char*)d_ws + head_bytes);
    float4*   ws2    = (float4*)((char*)d_ws + head_bytes + sorted_bytes);

    hipMemsetAsync(hist, 0, hist_bytes, stream);
    k_hist<<<nc, 256, 0, stream>>>(xs, inds, N, hist);
    k_scan<<<1, 1024, 0, stream>>>(hist, cursor);
    k_scatter<<<nc, 256, 0, stream>>>(xs, inds, N, cursor, sorted);

    const int direct = (ws_size < need_A) ? 1 : 0;
    k_main<<<nc * 8, 256, 0, stream>>>(sorted, params,
                                       direct ? nullptr : ws2,
                                       (float4*)out, N, nc, band_sz, direct);
    if (!direct)
        k_final<<<nc, 256, 0, stream>>>(sorted, ws2, (float4*)out, N, nc);
}